// Round 1
// baseline (283.575 us; speedup 1.0000x reference)
//
#include <hip/hip_runtime.h>
#include <math.h>

// Problem constants (from reference)
#define BATCH 4
#define N_ANCHORS 211200
#define CHANNELS 256
#define FM_H 200
#define FM_W 176
#define NKP 4096
#define PLANE (FM_H * FM_W)                   // 35200 floats

#define BOXES_ELEMS (BATCH * N_ANCHORS * 7)   // 5,913,600

// ---------------------------------------------------------------------------
// BEV strips: partition each (b,c) plane into 5 y-strips of 40 rows (y0 in
// [40q, 40q+40)), stage 41 rows (28.9 KB) in LDS -> 5 blocks/CU instead of
// the old whole-plane 140.8 KB -> 1 block/CU. y0 ranges 0..200 (200 = fully
// masked tap, q clamped to 4; q=4 strip needs only rows 160..199).
// ---------------------------------------------------------------------------
#define QSTRIPS 5
#define ROWS_PER_STRIP 40
#define STRIP_ROWS 41                          // 41*176*4 = 28864 B
#define BEV_BLOCKS (BATCH * CHANNELS * QSTRIPS)  // 5120

// Decode: 512 boxes/block so the LDS footprint (2*14336 = 28672 B) fits the
// same union as a bev strip -> decode blocks also get 5 blocks/CU.
#define DEC_BOXES 512
#define DEC_FLOATS (DEC_BOXES * 7)             // 3584
#define DEC_VEC4 (DEC_FLOATS / 4)              // 896
#define DEC_BLOCKS ((BATCH * N_ANCHORS) / DEC_BOXES)  // 1650 exactly

// ---------------------------------------------------------------------------
// Kernel 1: per-(b,k) keypoint transform, computed ONCE (was recomputed by
// every plane block: 4 fdiv sequences x 4096 kp x 1024+ blocks of pure VALU).
// Record (16 B): meta = yc0 | xc0<<8 | q<<16 | vy0<<20 | vy1<<21 | vx1<<22,
// wx, wy, pad. x0 is always a valid column (ix in [0,175.89]); y0 in [0,200].
// ---------------------------------------------------------------------------
__global__ __launch_bounds__(256) void kp_transform_kernel(
    const float* __restrict__ kp,        // [B, K, 3]
    float4* __restrict__ rec)            // [B*K] records in d_ws
{
    const int t = blockIdx.x * 256 + threadIdx.x;   // 0..16383
    const float kx = kp[t * 3 + 0];
    const float ky = kp[t * 3 + 1];

    // Verbatim math from the verified kernel (keeps absmax behavior).
    float ix_idx = kx / 0.4f;
    float iy_idx = (ky + 40.0f) / 0.4f;
    ix_idx = fminf(fmaxf(ix_idx, 0.0f), (float)(FM_W - 1));
    iy_idx = fminf(fmaxf(iy_idx, 0.0f), (float)(FM_H - 1));
    float nx = 2.0f * (ix_idx / (float)(FM_W - 2)) - 1.0f;
    float ny = 2.0f * (iy_idx / (float)(FM_H - 2)) - 1.0f;
    // grid flip: width coord gets ny, height coord gets nx
    float ix = (ny + 1.0f) * 0.5f * (float)(FM_W - 1);
    float iy = (nx + 1.0f) * 0.5f * (float)(FM_H - 1);

    float x0f = floorf(ix);
    float y0f = floorf(iy);
    float wx = ix - x0f;
    float wy = iy - y0f;
    int x0 = (int)x0f;      // always in [0, 175]
    int y0 = (int)y0f;      // in [0, 200]

    int q = min(y0 / ROWS_PER_STRIP, QSTRIPS - 1);
    unsigned vy0 = (y0     <= FM_H - 1) ? 1u : 0u;
    unsigned vy1 = (y0 + 1 <= FM_H - 1) ? 1u : 0u;
    unsigned vx1 = (x0 + 1 <= FM_W - 1) ? 1u : 0u;
    int yc0 = min(y0, FM_H - 1);

    unsigned meta = (unsigned)yc0 | ((unsigned)x0 << 8) | ((unsigned)q << 16)
                  | (vy0 << 20) | (vy1 << 21) | (vx1 << 22);
    float4 r;
    r.x = __uint_as_float(meta);
    r.y = wx;
    r.z = wy;
    r.w = 0.0f;
    rec[t] = r;
}

// ---------------------------------------------------------------------------
// Kernel 2: fused bev-gather (strip blocks) + box decode. 28.9 KB LDS union
// -> 5 blocks/CU, 20 waves/CU; decode's 71 MB stream overlaps bev's 161 MB.
//
// bev block mapping (XCD-grouped, bid%8 round-robin heuristic): XCD x owns
// planes [x*128, x*128+128); the 5 strips of a plane are consecutive blocks
// on the SAME XCD so their scattered 4B output writes into the same 16 KB
// outp range merge in one L2 (no cross-XCD partial-line write amplification),
// and the 1-row strip overlaps hit L2.
// ---------------------------------------------------------------------------
__global__ __launch_bounds__(256, 5) void fused_kernel(
    const float* __restrict__ deltas,
    const float* __restrict__ anchors,
    const float* __restrict__ fm,          // [B, C, H, W]
    const float4* __restrict__ rec,        // [B*K] precomputed records
    float* __restrict__ out_boxes,
    float* __restrict__ out_bev)           // [B, C, K]
{
    __shared__ union alignas(16) {
        struct { float d[DEC_FLOATS]; float a[DEC_FLOATS]; } dec;  // 28672 B
        float strip[STRIP_ROWS * FM_W];                            // 28864 B
    } sm;

    const int tid = threadIdx.x;
    const int bid = blockIdx.x;

    if (bid < BEV_BLOCKS) {
        // ---- BEV strip block ----
        const int x = bid & 7;
        const int j = bid >> 3;                       // 0..639 per XCD
        const int plane = x * (BATCH * CHANNELS / 8) + j / QSTRIPS;
        const int q = j - (j / QSTRIPS) * QSTRIPS;    // 0..4
        const int r0 = q * ROWS_PER_STRIP;
        const int cnt = min(STRIP_ROWS, FM_H - r0);   // 41, or 40 for q=4

        // Stage strip rows [r0, r0+cnt) -> LDS, coalesced float4.
        const float4* gp = (const float4*)(fm + (size_t)plane * PLANE + r0 * FM_W);
        float4* lp = (float4*)sm.strip;
        const int nv4 = cnt * (FM_W / 4);             // 1804 / 1760
        for (int i = tid; i < nv4; i += 256) lp[i] = gp[i];
        __syncthreads();

        const int b = plane / CHANNELS;
        const float4* rb = rec + (size_t)b * NKP;
        float* outp = out_bev + (size_t)plane * NKP;

        for (int k = tid; k < NKP; k += 256) {
            float4 rr = rb[k];
            unsigned meta = __float_as_uint(rr.x);
            if (((meta >> 16) & 0xFu) != (unsigned)q) continue;

            int yc0 = meta & 0xFF;
            int xc0 = (meta >> 8) & 0xFF;
            float fy0 = (float)((meta >> 20) & 1u);
            int dy1 = (meta >> 21) & 1;
            int dx1 = (meta >> 22) & 1;
            float fy1 = (float)dy1;
            float fx1 = (float)dx1;
            float wx = rr.y, wy = rr.z;

            int row0 = yc0 - r0;                      // in [0, cnt-1]
            int row1 = row0 + dy1;                    // masked tap re-reads row0
            int c1 = xc0 + dx1;                       // masked tap re-reads xc0

            float v00 = sm.strip[row0 * FM_W + xc0];
            float v01 = sm.strip[row0 * FM_W + c1];
            float v10 = sm.strip[row1 * FM_W + xc0];
            float v11 = sm.strip[row1 * FM_W + c1];

            float r = v00 * ((1.0f - wx) * (1.0f - wy)) * fy0
                    + v01 * (wx * (1.0f - wy)) * (fy0 * fx1)
                    + v10 * ((1.0f - wx) * wy) * fy1
                    + v11 * (wx * wy) * (fy1 * fx1);

            outp[k] = r;
        }
    } else {
        // ---- decode block: 512 boxes, LDS-staged, stride-7 conflict-free ----
        const int dec = bid - BEV_BLOCKS;
        const size_t base = (size_t)dec * DEC_FLOATS;   // 14336 B aligned

        const float4* gd = (const float4*)(deltas  + base);
        const float4* ga = (const float4*)(anchors + base);
        float4* ldd4 = (float4*)sm.dec.d;
        float4* lda4 = (float4*)sm.dec.a;
        for (int i = tid; i < DEC_VEC4; i += 256) {
            ldd4[i] = gd[i];
            lda4[i] = ga[i];
        }
        __syncthreads();

#pragma unroll
        for (int m = 0; m < DEC_BOXES / 256; ++m) {
            int box = tid + m * 256;
            float* d = sm.dec.d + box * 7;
            float* a = sm.dec.a + box * 7;
            float aw = a[3], al = a[4], ah = a[5];
            float dn = sqrtf(aw * aw + al * al);
            float o0 = d[0] * dn + a[0];
            float o1 = d[1] * dn + a[1];
            float o2 = d[2] * ah + a[2];
            float o3 = expf(d[3]) * aw;
            float o4 = expf(d[4]) * al;
            float o5 = expf(d[5]) * ah;
            float o6 = d[6] + a[6];
            d[0] = o0; d[1] = o1; d[2] = o2; d[3] = o3;
            d[4] = o4; d[5] = o5; d[6] = o6;
        }
        __syncthreads();

        float4* go = (float4*)(out_boxes + base);
        for (int i = tid; i < DEC_VEC4; i += 256) go[i] = ldd4[i];
    }
}

extern "C" void kernel_launch(void* const* d_in, const int* in_sizes, int n_in,
                              void* d_out, int out_size, void* d_ws, size_t ws_size,
                              hipStream_t stream)
{
    const float* deltas  = (const float*)d_in[0];
    const float* anchors = (const float*)d_in[1];
    const float* fm      = (const float*)d_in[2];
    const float* kp      = (const float*)d_in[3];

    float* out_boxes = (float*)d_out;
    float* out_bev   = (float*)d_out + BOXES_ELEMS;

    float4* rec = (float4*)d_ws;   // 16384 * 16 B = 256 KiB of workspace

    kp_transform_kernel<<<(BATCH * NKP) / 256, 256, 0, stream>>>(kp, rec);

    fused_kernel<<<BEV_BLOCKS + DEC_BLOCKS, 256, 0, stream>>>(
        deltas, anchors, fm, rec, out_boxes, out_bev);
}

// Round 2
// 258.501 us; speedup vs baseline: 1.0970x; 1.0970x over previous
//
#include <hip/hip_runtime.h>
#include <math.h>

// Problem constants (from reference)
#define BATCH 4
#define N_ANCHORS 211200
#define CHANNELS 256
#define FM_H 200
#define FM_W 176
#define NKP 4096
#define PLANE (FM_H * FM_W)                   // 35200 floats

#define BOXES_ELEMS (BATCH * N_ANCHORS * 7)   // 5,913,600

// BEV strips: 5 y-strips of 40 rows per plane; stage 41 rows (28864 B) in LDS
// -> 5 blocks/CU.
#define QSTRIPS 5
#define ROWS_PER_STRIP 40
#define STRIP_ROWS 41
#define BEV_BLOCKS (BATCH * CHANNELS * QSTRIPS)       // 5120

// Decode: 512 boxes/block -> LDS union fits the bev strip footprint.
#define DEC_BOXES 512
#define DEC_FLOATS (DEC_BOXES * 7)                    // 3584
#define DEC_VEC4 (DEC_FLOATS / 4)                     // 896 = 3*256 + 128
#define DEC_BLOCKS ((BATCH * N_ANCHORS) / DEC_BOXES)  // 1650

// Block interleave: period 32 = 24 bev + 8 dec (24 % 8 == 0 keeps bevIdx&7 ==
// hardware XCD). 206 full periods, then 2 dec + 176 bev tail.
#define FULL_PERIODS 206
#define INTERLEAVED (FULL_PERIODS * 32)               // 6592
#define TOTAL_BLOCKS (BEV_BLOCKS + DEC_BLOCKS)        // 6770

#define NBUCKET (BATCH * QSTRIPS)                     // 20

// Async global->LDS, 16B per lane (wave-uniform LDS base + lane*16; our
// staging index is lane-linear per wave, so the linear layout matches).
#define GLL(g, l) __builtin_amdgcn_global_load_lds(                        \
    (const __attribute__((address_space(1))) void*)(g),                    \
    (__attribute__((address_space(3))) void*)(l), 16, 0, 0)

// ---------------------------------------------------------------------------
// Kernel 1: keypoint transform + bucket by (b, strip q). Computed ONCE.
// Record (16 B): meta = yc0 | x0<<8 | k<<16 | vy0<<28 | vy1<<29 | vx1<<30,
// wx, wy, pad. x0 always in [0,175]; y0 in [0,200] (200 = fully masked).
// Bucket slots assigned via LDS-aggregated atomics (20 global atomics/block).
// ---------------------------------------------------------------------------
__global__ __launch_bounds__(256) void kp_transform_kernel(
    const float* __restrict__ kp,        // [B, K, 3]
    int* __restrict__ counts,            // [20] pre-zeroed bucket sizes
    float4* __restrict__ bucket)         // [20 * NKP] records
{
    __shared__ int lcnt[NBUCKET];
    __shared__ int lbase[NBUCKET];
    const int tid = threadIdx.x;
    if (tid < NBUCKET) lcnt[tid] = 0;
    __syncthreads();

    const int t = blockIdx.x * 256 + tid;   // 0..16383
    const int b = t >> 12;
    const int k = t & (NKP - 1);
    const float kx = kp[t * 3 + 0];
    const float ky = kp[t * 3 + 1];

    // Verbatim math from the verified kernel (keeps absmax behavior).
    float ix_idx = kx / 0.4f;
    float iy_idx = (ky + 40.0f) / 0.4f;
    ix_idx = fminf(fmaxf(ix_idx, 0.0f), (float)(FM_W - 1));
    iy_idx = fminf(fmaxf(iy_idx, 0.0f), (float)(FM_H - 1));
    float nx = 2.0f * (ix_idx / (float)(FM_W - 2)) - 1.0f;
    float ny = 2.0f * (iy_idx / (float)(FM_H - 2)) - 1.0f;
    // grid flip: width coord gets ny, height coord gets nx
    float ix = (ny + 1.0f) * 0.5f * (float)(FM_W - 1);
    float iy = (nx + 1.0f) * 0.5f * (float)(FM_H - 1);

    float x0f = floorf(ix);
    float y0f = floorf(iy);
    float wx = ix - x0f;
    float wy = iy - y0f;
    int x0 = (int)x0f;      // in [0, 175]
    int y0 = (int)y0f;      // in [0, 200]

    int q = min(y0 / ROWS_PER_STRIP, QSTRIPS - 1);
    unsigned vy0 = (y0     <= FM_H - 1) ? 1u : 0u;
    unsigned vy1 = (y0 + 1 <= FM_H - 1) ? 1u : 0u;
    unsigned vx1 = (x0 + 1 <= FM_W - 1) ? 1u : 0u;
    int yc0 = min(y0, FM_H - 1);

    unsigned meta = (unsigned)yc0 | ((unsigned)x0 << 8) | ((unsigned)k << 16)
                  | (vy0 << 28) | (vy1 << 29) | (vx1 << 30);

    const int bq = b * QSTRIPS + q;
    int rank = atomicAdd(&lcnt[bq], 1);
    __syncthreads();
    if (tid < NBUCKET)
        lbase[tid] = lcnt[tid] ? atomicAdd(&counts[tid], lcnt[tid]) : 0;
    __syncthreads();

    float4 r;
    r.x = __uint_as_float(meta);
    r.y = wx;
    r.z = wy;
    r.w = 0.0f;
    bucket[(size_t)bq * NKP + lbase[bq] + rank] = r;
}

// ---------------------------------------------------------------------------
// Kernel 2: fused bev-gather (bucketed strip blocks) + box decode.
// bev: stage 41-row strip via global_load_lds, then a DENSE scan of only this
// strip's bucket (~819 records, all lanes active) — the round-1 version
// scanned all 4096 with 80% discarded.
// ---------------------------------------------------------------------------
__global__ __launch_bounds__(256, 5) void fused_kernel(
    const float* __restrict__ deltas,
    const float* __restrict__ anchors,
    const float* __restrict__ fm,          // [B, C, H, W]
    const int* __restrict__ counts,        // [20]
    const float4* __restrict__ bucket,     // [20 * NKP]
    float* __restrict__ out_boxes,
    float* __restrict__ out_bev)           // [B, C, K]
{
    __shared__ union alignas(16) {
        struct { float d[DEC_FLOATS]; float a[DEC_FLOATS]; } dec;  // 28672 B
        float strip[STRIP_ROWS * FM_W];                            // 28864 B
    } sm;

    const int tid = threadIdx.x;
    const int bid = blockIdx.x;

    // ---- interleaved block-role mapping (XCD-alignment preserving) ----
    bool isDec;
    int bevIdx = 0, decIdx = 0;
    if (bid < INTERLEAVED) {
        int p = bid & 31;
        int period = bid >> 5;
        if (p < 24) { isDec = false; bevIdx = period * 24 + p; }
        else        { isDec = true;  decIdx = period * 8 + (p - 24); }
    } else {
        int r = bid - INTERLEAVED;
        if (r < 2) { isDec = true;  decIdx = FULL_PERIODS * 8 + r; }
        else       { isDec = false; bevIdx = FULL_PERIODS * 24 + (r - 2); }
    }

    if (!isDec) {
        // ---- BEV strip block ----
        const int x = bevIdx & 7;                       // == hardware XCD
        const int j = bevIdx >> 3;                      // 0..639 per XCD
        const int plane = x * (BATCH * CHANNELS / 8) + j / QSTRIPS;
        const int q = j - (j / QSTRIPS) * QSTRIPS;      // 0..4
        const int r0 = q * ROWS_PER_STRIP;
        const int cnt_rows = min(STRIP_ROWS, FM_H - r0);  // 41, or 40 for q=4
        const int nv4 = cnt_rows * (FM_W / 4);            // 1804 / 1760

        // Stage strip -> LDS (async direct-to-LDS, 16B/lane, lane-linear).
        const float* gsrc = fm + (size_t)plane * PLANE + r0 * FM_W;
        const int nfull = nv4 >> 8;
        for (int it = 0; it < nfull; ++it) {
            int idx = (it << 8) + tid;
            GLL(gsrc + idx * 4, &sm.strip[idx * 4]);
        }
        {
            int rem = nv4 & 255;
            if (tid < rem) {
                int idx = (nv4 & ~255) + tid;
                GLL(gsrc + idx * 4, &sm.strip[idx * 4]);
            }
        }

        // Uniform setup while the stage is in flight.
        const int b = plane / CHANNELS;
        const int bq = b * QSTRIPS + q;
        const int cnt = counts[bq];
        const float4* bk = bucket + (size_t)bq * NKP;
        float* outp = out_bev + (size_t)plane * NKP;

        __syncthreads();   // drains vmcnt (global_load_lds) for all waves

        // Dense bucket scan: ~3.2 iters/thread, all lanes active.
        for (int i = tid; i < cnt; i += 256) {
            float4 rr = bk[i];
            unsigned meta = __float_as_uint(rr.x);
            int yc0 = meta & 0xFF;
            int xc0 = (meta >> 8) & 0xFF;
            int k   = (meta >> 16) & 0xFFF;
            float fy0 = (float)((meta >> 28) & 1u);
            int dy1 = (meta >> 29) & 1;
            int dx1 = (meta >> 30) & 1;
            float fy1 = (float)dy1;
            float fx1 = (float)dx1;
            float wx = rr.y, wy = rr.z;
            float ex = 1.0f - wx, ey = 1.0f - wy;

            int a0 = (yc0 - r0) * FM_W + xc0;
            int a1 = a0 + dy1 * FM_W;
            float v00 = sm.strip[a0];
            float v01 = sm.strip[a0 + dx1];
            float v10 = sm.strip[a1];
            float v11 = sm.strip[a1 + dx1];

            float w00 = ex * ey * fy0;
            float w01 = wx * ey * (fy0 * fx1);
            float w10 = ex * wy * fy1;
            float w11 = wx * wy * (fy1 * fx1);

            outp[k] = v00 * w00 + v01 * w01 + v10 * w10 + v11 * w11;
        }
    } else {
        // ---- decode block: 512 boxes, LDS-staged, stride-7 conflict-free ----
        const size_t base = (size_t)decIdx * DEC_FLOATS;   // 14336 B aligned
        const float* gd = deltas  + base;
        const float* ga = anchors + base;

#pragma unroll
        for (int it = 0; it < 3; ++it) {                   // 3*256 of 896
            int idx = (it << 8) + tid;
            GLL(gd + idx * 4, &sm.dec.d[idx * 4]);
            GLL(ga + idx * 4, &sm.dec.a[idx * 4]);
        }
        if (tid < 128) {                                   // tail 128
            int idx = 768 + tid;
            GLL(gd + idx * 4, &sm.dec.d[idx * 4]);
            GLL(ga + idx * 4, &sm.dec.a[idx * 4]);
        }
        __syncthreads();

#pragma unroll
        for (int m = 0; m < DEC_BOXES / 256; ++m) {
            int box = tid + m * 256;
            float* d = sm.dec.d + box * 7;
            float* a = sm.dec.a + box * 7;
            float aw = a[3], al = a[4], ah = a[5];
            float dn = sqrtf(aw * aw + al * al);
            float o0 = d[0] * dn + a[0];
            float o1 = d[1] * dn + a[1];
            float o2 = d[2] * ah + a[2];
            float o3 = expf(d[3]) * aw;
            float o4 = expf(d[4]) * al;
            float o5 = expf(d[5]) * ah;
            float o6 = d[6] + a[6];
            d[0] = o0; d[1] = o1; d[2] = o2; d[3] = o3;
            d[4] = o4; d[5] = o5; d[6] = o6;
        }
        __syncthreads();

        const float4* ldd4 = (const float4*)sm.dec.d;
        float4* go = (float4*)(out_boxes + base);
        for (int i = tid; i < DEC_VEC4; i += 256) go[i] = ldd4[i];
    }
}

extern "C" void kernel_launch(void* const* d_in, const int* in_sizes, int n_in,
                              void* d_out, int out_size, void* d_ws, size_t ws_size,
                              hipStream_t stream)
{
    const float* deltas  = (const float*)d_in[0];
    const float* anchors = (const float*)d_in[1];
    const float* fm      = (const float*)d_in[2];
    const float* kp      = (const float*)d_in[3];

    float* out_boxes = (float*)d_out;
    float* out_bev   = (float*)d_out + BOXES_ELEMS;

    // Workspace layout: [0,80) bucket counts, [256, 256+1.31MB) records.
    int*    counts = (int*)d_ws;
    float4* bucket = (float4*)((char*)d_ws + 256);

    hipMemsetAsync(d_ws, 0, NBUCKET * sizeof(int), stream);   // ws is re-poisoned each iter

    kp_transform_kernel<<<(BATCH * NKP) / 256, 256, 0, stream>>>(kp, counts, bucket);

    fused_kernel<<<TOTAL_BLOCKS, 256, 0, stream>>>(
        deltas, anchors, fm, counts, bucket, out_boxes, out_bev);
}

// Round 3
// 255.611 us; speedup vs baseline: 1.1094x; 1.0113x over previous
//
#include <hip/hip_runtime.h>
#include <math.h>

// Problem constants (from reference)
#define BATCH 4
#define N_ANCHORS 211200
#define CHANNELS 256
#define FM_H 200
#define FM_W 176
#define NKP 4096
#define PLANE (FM_H * FM_W)                   // 35200 floats

#define BOXES_ELEMS (BATCH * N_ANCHORS * 7)   // 5,913,600

// BEV strips: 5 y-strips of 40 rows per plane; stage 41 rows (28864 B) in LDS.
#define QSTRIPS 5
#define ROWS_PER_STRIP 40
#define STRIP_ROWS 41
#define STRIP_FLOATS (STRIP_ROWS * FM_W)              // 7216
#define BEV_BLOCKS (BATCH * CHANNELS * QSTRIPS)       // 5120

// Decode: 512 boxes/block (1 box/thread at 512 threads).
#define DEC_BOXES 512
#define DEC_FLOATS (DEC_BOXES * 7)                    // 3584
#define DEC_VEC4 (DEC_FLOATS / 4)                     // 896
#define DEC_BLOCKS ((BATCH * N_ANCHORS) / DEC_BOXES)  // 1650

// Block interleave: period 32 = 24 bev + 8 dec (24 % 8 == 0 keeps bevIdx&7 ==
// hardware XCD). 206 full periods, then 2 dec + 176 bev tail.
#define FULL_PERIODS 206
#define INTERLEAVED (FULL_PERIODS * 32)               // 6592
#define TOTAL_BLOCKS (BEV_BLOCKS + DEC_BLOCKS)        // 6770

#define NBUCKET (BATCH * QSTRIPS)                     // 20

// Async global->LDS, 16B/lane (wave-uniform LDS base + lane*16; our staging
// index is lane-linear per wave, so the linear layout matches).
#define GLL(g, l) __builtin_amdgcn_global_load_lds(                        \
    (const __attribute__((address_space(1))) void*)(g),                    \
    (__attribute__((address_space(3))) void*)(l), 16, 0, 0)

// ---------------------------------------------------------------------------
// Kernel 1: keypoint transform + stable k-sorted bucketing, one block per
// batch b (4 blocks x 1024 threads, thread t handles k = 4t..4t+3).
//
// Record (16 B): meta = a0 | dx<<13 | dy<<14 | k<<15, wx, WY0, WY1 where
//   a0  = strip-local tap address (rowoff*176 + x0, 13 bits)
//   dx  = x1-valid (adds 1 col),   dy = y1-valid (adds 176)
//   WY0 = (1-wy)*fy0, WY1 = wy*fy1   (row-valid flags folded into weights)
// All per-record decode work the 5120 strip blocks used to redo is now here.
//
// Stable counting sort by (q) preserving k order: per-thread counts of the 5
// buckets packed into two ULLs (13-bit fields), inclusive prefix via in-wave
// shfl scan + cross-wave LDS combine (2 barriers). Writes counts[] directly:
// no global atomics, no memset launch.
// ---------------------------------------------------------------------------
__global__ __launch_bounds__(1024) void kp_transform_sort_kernel(
    const float* __restrict__ kp,        // [B, K, 3]
    int* __restrict__ counts,            // [20]
    float4* __restrict__ bucket)         // [20 * NKP] records
{
    __shared__ unsigned long long w0[16], w1[16];

    const int b   = blockIdx.x;
    const int tid = threadIdx.x;
    const int lane = tid & 63;
    const int wid  = tid >> 6;

    // Load 4 keypoints (12 consecutive floats = 3 float4).
    const float4* kp4 = (const float4*)(kp + (size_t)b * NKP * 3) + tid * 3;
    float4 p0 = kp4[0], p1 = kp4[1], p2 = kp4[2];
    float kx[4] = {p0.x, p0.w, p1.z, p2.y};
    float ky[4] = {p0.y, p1.x, p1.w, p2.z};

    unsigned metaJ[4];
    float wxJ[4], wy0J[4], wy1J[4];
    int qJ[4];
    unsigned long long P0 = 0, P1 = 0;

#pragma unroll
    for (int j = 0; j < 4; ++j) {
        const int k = tid * 4 + j;
        // Verbatim transform math (keeps absmax behavior).
        float ix_idx = kx[j] / 0.4f;
        float iy_idx = (ky[j] + 40.0f) / 0.4f;
        ix_idx = fminf(fmaxf(ix_idx, 0.0f), (float)(FM_W - 1));
        iy_idx = fminf(fmaxf(iy_idx, 0.0f), (float)(FM_H - 1));
        float nx = 2.0f * (ix_idx / (float)(FM_W - 2)) - 1.0f;
        float ny = 2.0f * (iy_idx / (float)(FM_H - 2)) - 1.0f;
        // grid flip: width coord gets ny, height coord gets nx
        float ix = (ny + 1.0f) * 0.5f * (float)(FM_W - 1);
        float iy = (nx + 1.0f) * 0.5f * (float)(FM_H - 1);

        float x0f = floorf(ix);
        float y0f = floorf(iy);
        float wx = ix - x0f;
        float wy = iy - y0f;
        int x0 = (int)x0f;      // in [0, 175]
        int y0 = (int)y0f;      // in [0, 199] for this geometry (200 kept safe)

        int q = min(y0 / ROWS_PER_STRIP, QSTRIPS - 1);
        int yc0 = min(y0, FM_H - 1);
        int rowoff = yc0 - q * ROWS_PER_STRIP;          // [0, 40]
        int dx = (x0 + 1 <= FM_W - 1) ? 1 : 0;
        int dy = (y0 + 1 <= FM_H - 1) ? 1 : 0;
        float fy0 = (y0 <= FM_H - 1) ? 1.0f : 0.0f;

        unsigned a0 = (unsigned)(rowoff * FM_W + x0);   // 13 bits
        metaJ[j] = a0 | ((unsigned)dx << 13) | ((unsigned)dy << 14)
                 | ((unsigned)k << 15);
        wxJ[j]  = wx;
        wy0J[j] = (1.0f - wy) * fy0;
        wy1J[j] = wy * (float)dy;
        qJ[j]   = q;

        // bump packed count: q0..q2 in P0, q3..q4 in P1 (13-bit fields)
        if (q < 3) P0 += 1ull << (13 * q);
        else       P1 += 1ull << (13 * (q - 3));
    }

    // Inclusive scan of (P0,P1) over 1024 threads: in-wave shfl + cross-wave.
    unsigned long long v0 = P0, v1 = P1;
#pragma unroll
    for (int off = 1; off < 64; off <<= 1) {
        unsigned long long t0 = __shfl_up(v0, off);
        unsigned long long t1 = __shfl_up(v1, off);
        if (lane >= off) { v0 += t0; v1 += t1; }
    }
    if (lane == 63) { w0[wid] = v0; w1[wid] = v1; }
    __syncthreads();
    if (wid == 0 && lane < 16) {
        unsigned long long a0s = w0[lane], a1s = w1[lane];
#pragma unroll
        for (int off = 1; off < 16; off <<= 1) {
            unsigned long long t0 = __shfl_up(a0s, off);
            unsigned long long t1 = __shfl_up(a1s, off);
            if (lane >= off) { a0s += t0; a1s += t1; }
        }
        w0[lane] = a0s; w1[lane] = a1s;
    }
    __syncthreads();

    unsigned long long base0 = wid ? w0[wid - 1] : 0ull;
    unsigned long long base1 = wid ? w1[wid - 1] : 0ull;
    unsigned long long ex0 = v0 + base0 - P0;   // exclusive prefix for this thread
    unsigned long long ex1 = v1 + base1 - P1;
    unsigned long long tot0 = w0[15], tot1 = w1[15];

    if (tid < QSTRIPS) {
        unsigned long long t = (tid < 3) ? tot0 : tot1;
        int sh = (tid < 3) ? 13 * tid : 13 * (tid - 3);
        counts[b * QSTRIPS + tid] = (int)((t >> sh) & 0x1FFFull);
    }

    int slot[QSTRIPS];
#pragma unroll
    for (int q = 0; q < QSTRIPS; ++q) {
        unsigned long long e = (q < 3) ? ex0 : ex1;
        int sh = (q < 3) ? 13 * q : 13 * (q - 3);
        slot[q] = (int)((e >> sh) & 0x1FFFull);
    }

#pragma unroll
    for (int j = 0; j < 4; ++j) {
        int q = qJ[j];
        float4 r;
        r.x = __uint_as_float(metaJ[j]);
        r.y = wxJ[j];
        r.z = wy0J[j];
        r.w = wy1J[j];
        bucket[(size_t)(b * QSTRIPS + q) * NKP + slot[q]] = r;
        slot[q]++;
    }
}

// ---------------------------------------------------------------------------
// Kernel 2: fused bev-gather (k-sorted bucketed strip blocks) + box decode.
// 512 threads, 4 blocks/CU -> 32 waves/CU. Bucket records are preloaded into
// registers BEFORE the stage barrier (kills the post-barrier L2-latency
// chain); scan body is ~4 LDS taps + ~10 VALU thanks to precomputed records.
// ---------------------------------------------------------------------------
__global__ __launch_bounds__(512, 8) void fused_kernel(
    const float* __restrict__ deltas,
    const float* __restrict__ anchors,
    const float* __restrict__ fm,          // [B, C, H, W]
    const int* __restrict__ counts,        // [20]
    const float4* __restrict__ bucket,     // [20 * NKP]
    float* __restrict__ out_boxes,
    float* __restrict__ out_bev)           // [B, C, K]
{
    __shared__ union alignas(16) {
        struct { float d[DEC_FLOATS]; float a[DEC_FLOATS]; } dec;  // 28672 B
        float strip[STRIP_FLOATS];                                 // 28864 B
    } sm;

    const int tid = threadIdx.x;
    const int bid = blockIdx.x;

    // ---- interleaved block-role mapping (XCD-alignment preserving) ----
    bool isDec;
    int bevIdx = 0, decIdx = 0;
    if (bid < INTERLEAVED) {
        int p = bid & 31;
        int period = bid >> 5;
        if (p < 24) { isDec = false; bevIdx = period * 24 + p; }
        else        { isDec = true;  decIdx = period * 8 + (p - 24); }
    } else {
        int r = bid - INTERLEAVED;
        if (r < 2) { isDec = true;  decIdx = FULL_PERIODS * 8 + r; }
        else       { isDec = false; bevIdx = FULL_PERIODS * 24 + (r - 2); }
    }

    if (!isDec) {
        // ---- BEV strip block ----
        const int x = bevIdx & 7;                       // == hardware XCD
        const int j = bevIdx >> 3;                      // 0..639 per XCD
        const int plane = x * (BATCH * CHANNELS / 8) + j / QSTRIPS;
        const int q = j - (j / QSTRIPS) * QSTRIPS;      // 0..4
        const int r0 = q * ROWS_PER_STRIP;
        const int cnt_rows = min(STRIP_ROWS, FM_H - r0);  // 41 (40 for q=4)
        const int nv4 = cnt_rows * (FM_W / 4);            // 1804 / 1760

        // Stage strip -> LDS (async direct-to-LDS, 16B/lane, lane-linear).
        const float* gsrc = fm + (size_t)plane * PLANE + r0 * FM_W;
        for (int i = tid; i < nv4; i += 512)
            GLL(gsrc + i * 4, &sm.strip[i * 4]);

        // Uniform setup + register preload of bucket records while the
        // stage is in flight (slots >= cnt hold garbage; masked at use).
        const int b  = plane / CHANNELS;
        const int bq = b * QSTRIPS + q;
        const int cnt = counts[bq];
        const float4* bk = bucket + (size_t)bq * NKP;
        float* outp = out_bev + (size_t)plane * NKP;

        float4 rA = bk[tid];
        float4 rB = bk[tid + 512];

        __syncthreads();   // drains vmcnt (global_load_lds) for all waves

#define PROC(rr)                                                            \
        {                                                                   \
            unsigned meta = __float_as_uint((rr).x);                        \
            int a0  = meta & 0x1FFF;                                        \
            int dx  = (meta >> 13) & 1;                                     \
            int dyo = ((meta >> 14) & 1) * FM_W;                            \
            int k   = meta >> 15;                                           \
            float wx = (rr).y, WY0 = (rr).z, WY1 = (rr).w;                  \
            float v00 = sm.strip[a0];                                       \
            float v01 = sm.strip[a0 + dx];                                  \
            float v10 = sm.strip[a0 + dyo];                                 \
            float v11 = sm.strip[a0 + dyo + dx];                            \
            float ex  = 1.0f - wx;                                          \
            float wxm = wx * (float)dx;                                     \
            outp[k] = (v00 * ex + v01 * wxm) * WY0                          \
                    + (v10 * ex + v11 * wxm) * WY1;                         \
        }

        if (tid < cnt)        PROC(rA);
        if (tid + 512 < cnt)  PROC(rB);
        for (int i = 1024 + tid; i < cnt; i += 512) {  // rare (cnt > 1024)
            float4 rr = bk[i];
            PROC(rr);
        }
#undef PROC
    } else {
        // ---- decode block: 512 boxes, LDS-staged, stride-7 conflict-free ----
        const size_t base = (size_t)decIdx * DEC_FLOATS;   // 14336 B aligned
        const float* gd = deltas  + base;
        const float* ga = anchors + base;

        for (int i = tid; i < DEC_VEC4; i += 512) {        // 896 float4
            GLL(gd + i * 4, &sm.dec.d[i * 4]);
            GLL(ga + i * 4, &sm.dec.a[i * 4]);
        }
        __syncthreads();

        {
            float* d = sm.dec.d + tid * 7;
            float* a = sm.dec.a + tid * 7;
            float aw = a[3], al = a[4], ah = a[5];
            float dn = sqrtf(aw * aw + al * al);
            float o0 = d[0] * dn + a[0];
            float o1 = d[1] * dn + a[1];
            float o2 = d[2] * ah + a[2];
            float o3 = expf(d[3]) * aw;
            float o4 = expf(d[4]) * al;
            float o5 = expf(d[5]) * ah;
            float o6 = d[6] + a[6];
            d[0] = o0; d[1] = o1; d[2] = o2; d[3] = o3;
            d[4] = o4; d[5] = o5; d[6] = o6;
        }
        __syncthreads();

        const float4* ldd4 = (const float4*)sm.dec.d;
        float4* go = (float4*)(out_boxes + base);
        for (int i = tid; i < DEC_VEC4; i += 512) go[i] = ldd4[i];
    }
}

extern "C" void kernel_launch(void* const* d_in, const int* in_sizes, int n_in,
                              void* d_out, int out_size, void* d_ws, size_t ws_size,
                              hipStream_t stream)
{
    const float* deltas  = (const float*)d_in[0];
    const float* anchors = (const float*)d_in[1];
    const float* fm      = (const float*)d_in[2];
    const float* kp      = (const float*)d_in[3];

    float* out_boxes = (float*)d_out;
    float* out_bev   = (float*)d_out + BOXES_ELEMS;

    // Workspace: [0,80) bucket counts, [256, 256+1.31MB) records.
    int*    counts = (int*)d_ws;
    float4* bucket = (float4*)((char*)d_ws + 256);

    kp_transform_sort_kernel<<<BATCH, 1024, 0, stream>>>(kp, counts, bucket);

    fused_kernel<<<TOTAL_BLOCKS, 512, 0, stream>>>(
        deltas, anchors, fm, counts, bucket, out_boxes, out_bev);
}